// Round 9
// baseline (123.513 us; speedup 1.0000x reference)
//
#include <hip/hip_runtime.h>
#include <hip/hip_bf16.h>
#include <cstdint>
#include <cstddef>

// Problem constants: B=4, T=1024, E=512, H=64, d_k=8
#define T_DIM 1024
#define E_DIM 512

typedef short bf16x8 __attribute__((ext_vector_type(8)));
typedef float f32x4  __attribute__((ext_vector_type(4)));

// ---------------------------------------------------------------------------
// Kernel 0 `prep`: per-head proj blobs + W convert. grid 256 x 1024 thr,
// thread = (head, row). Writes:
//   projA_g [head][1024][8]  scaled by sqrt(scale*log2e) (score operands)
//   projT_g [head][8][1024]  unscaled (PV V-operand)
// Thread=row makes every projT_g store coalesced (consecutive lanes ->
// consecutive r at fixed d). Decouples the cos/transpose staging from the
// attention kernel so qattn's grid-512 occupancy no longer duplicates it
// (R8 lesson: extra waves only help if they bring no extra work).
// ---------------------------------------------------------------------------
__global__ __launch_bounds__(1024)
void prep_kernel(const float* __restrict__ x,
                 const float* __restrict__ theta,
                 const float* __restrict__ W,
                 __hip_bfloat16* __restrict__ projA_g, // [256][1024][8]
                 __hip_bfloat16* __restrict__ projT_g, // [256][8][1024]
                 __hip_bfloat16* __restrict__ w_bf)    // [512][512]
{
    const int head = blockIdx.x;        // 0..255
    const int tid  = threadIdx.x;       // 0..1023 = row
    const int b    = head >> 6;
    const int h    = head & 63;

    // Folded W fp32->bf16 convert (heads 0..63 cover 512*512/4 threads).
    {
        const int gid = head * 1024 + tid;
        if (gid < 65536) {
            const float4 v = *(const float4*)(W + gid * 4);
            alignas(8) __hip_bfloat16 ob[4] = {
                __float2bfloat16(v.x), __float2bfloat16(v.y),
                __float2bfloat16(v.z), __float2bfloat16(v.w)};
            *(uint2*)(w_bf + gid * 4) = *(const uint2*)ob;
        }
    }

    // sqrt((1/sqrt(8))*log2(e)): folds softmax scale + ln->log2 into the
    // score operands so e = exp2(raw mfma score).
    const float SA = 0.7142255f;
    float ctT[8], ctA[8];
#pragma unroll
    for (int d = 0; d < 8; ++d) {
        ctT[d] = __cosf(theta[d]);
        ctA[d] = ctT[d] * SA;
    }

    const float* xr = x + (size_t)b * T_DIM * E_DIM + (size_t)tid * E_DIM + h * 8;
    const float4 v0 = *(const float4*)(xr);
    const float4 v1 = *(const float4*)(xr + 4);
    float pr[8] = {v0.x, v0.y, v0.z, v0.w, v1.x, v1.y, v1.z, v1.w};
    alignas(16) __hip_bfloat16 ra[8];
    __hip_bfloat16* ptg = projT_g + (size_t)head * 8192 + tid;
#pragma unroll
    for (int d = 0; d < 8; ++d) {
        const float c = __cosf(pr[d]);
        ra[d] = __float2bfloat16(c * ctA[d]);
        ptg[d * 1024] = __float2bfloat16(c * ctT[d]);
    }
    *(uint4*)(projA_g + (size_t)head * 8192 + (size_t)tid * 8) = *(const uint4*)ra;
}

// ---------------------------------------------------------------------------
// Kernel A: lean MFMA attention. grid 512 = 256 heads x 2 q-halves, 1024 thr
// (2 blocks/CU, 8 waves/SIMD). Staging = ONE coalesced global_load_lds pass
// of the 16KB projA blob (1 chunk/thread). V-frags read straight from global
// projT_g with next-chunk register prefetch (16KB/head -> L1-resident,
// shared by both half-blocks). Inner math identical to verified R5-R8:
// scores via 16x16x32 bf16 MFMA (quad0 carries d), e = exp2(raw score)
// (operands pre-scaled), e-values feed PV A-operand in the score-MFMA's own
// k-permutation (pi trick, zero cross-lane traffic), B col 8 = ones -> den
// free in output col 8.
// ---------------------------------------------------------------------------
__global__ __launch_bounds__(1024)
void qattn_mfma(const __hip_bfloat16* __restrict__ projA_g, // [256][1024][8]
                const __hip_bfloat16* __restrict__ projT_g, // [256][8][1024]
                __hip_bfloat16* __restrict__ attn_out)      // [4096][512]
{
    __shared__ __hip_bfloat16 projA[T_DIM][8];   // 16 KB staged blob

    const int bid   = blockIdx.x;       // 0..511
    const int head  = bid >> 1;         // 0..255
    const int qhalf = bid & 1;
    const int b     = head >> 6;
    const int h     = head & 63;
    const int tid   = threadIdx.x;      // 0..1023
    const int lane  = tid & 63;
    const int wv    = tid >> 6;         // 0..15
    const int rlo   = lane & 15;
    const int quad  = lane >> 4;

    // Stage projA blob: chunk c = tid -> LDS row c (wave-uniform base).
    {
        const __hip_bfloat16* g = projA_g + (size_t)head * 8192 + (size_t)tid * 8;
        char* l = (char*)projA + (size_t)wv * 1024;
        __builtin_amdgcn_global_load_lds(
            (const __attribute__((address_space(1))) void*)g,
            (__attribute__((address_space(3))) void*)l, 16, 0, 0);
    }
    __syncthreads();

    const bf16x8 z8 = {};
    bf16x8 ones8;
#pragma unroll
    for (int j = 0; j < 8; ++j) ones8[j] = (short)0x3f80;  // bf16 1.0

    // This wave owns 32 queries (2 tiles of 16).
    const int q0 = qhalf * 512 + wv * 32;
    bf16x8 bq[2];
#pragma unroll
    for (int tl = 0; tl < 2; ++tl)
        bq[tl] = (quad == 0) ? *(const bf16x8*)&projA[q0 + tl * 16 + rlo][0]
                             : z8;

    f32x4 nacc[2] = {};

    // V-frag global base (valid for rlo<8 lanes only; exec-masked loads).
    const __hip_bfloat16* ptb =
        projT_g + (size_t)head * 8192 + (size_t)rlo * 1024 + quad * 4;
    uint2 nbv0 = {}, nbv1 = {};
    if (rlo < 8) {
        nbv0 = *(const uint2*)(ptb);
        nbv1 = *(const uint2*)(ptb + 16);
    }

    for (int kc = 0; kc < 32; ++kc) {           // 32-key chunks
        const int key0 = kc * 32;
        // Build V-frag from prefetched regs (pi order).
        bf16x8 bv;
        if (rlo < 8) {
            union { uint2 u[2]; bf16x8 v; } uu;
            uu.u[0] = nbv0;
            uu.u[1] = nbv1;
            bv = uu.v;
        } else {
            bv = (rlo == 8) ? ones8 : z8;
        }
        // Prefetch next chunk's V-frag (L1-resident after first sweep).
        const int key0n = (kc < 31) ? key0 + 32 : 0;
        if (rlo < 8) {
            nbv0 = *(const uint2*)(ptb + key0n);
            nbv1 = *(const uint2*)(ptb + key0n + 16);
        }
        // Key A-frags for the two 16-key halves.
        const bf16x8 ka0 =
            (quad == 0) ? *(const bf16x8*)&projA[key0 + rlo][0] : z8;
        const bf16x8 ka1 =
            (quad == 0) ? *(const bf16x8*)&projA[key0 + 16 + rlo][0] : z8;

#pragma unroll
        for (int tl = 0; tl < 2; ++tl) {
            f32x4 s0 = __builtin_amdgcn_mfma_f32_16x16x32_bf16(
                ka0, bq[tl], (f32x4){0.f, 0.f, 0.f, 0.f}, 0, 0, 0);
            f32x4 s1 = __builtin_amdgcn_mfma_f32_16x16x32_bf16(
                ka1, bq[tl], (f32x4){0.f, 0.f, 0.f, 0.f}, 0, 0, 0);
            alignas(16) __hip_bfloat16 af8[8];
#pragma unroll
            for (int r = 0; r < 4; ++r) {
                af8[r]     = __float2bfloat16(__builtin_amdgcn_exp2f(s0[r]));
                af8[4 + r] = __float2bfloat16(__builtin_amdgcn_exp2f(s1[r]));
            }
            nacc[tl] = __builtin_amdgcn_mfma_f32_16x16x32_bf16(
                *(const bf16x8*)af8, bv, nacc[tl], 0, 0, 0);
        }
    }

    // Epilogue: nacc[tl][r] = num[q=q0+tl*16+quad*4+r][d=rlo]; col 8 = den.
    const int denSrc = (lane & 48) | 8;   // lane with rlo==8 in same quad
#pragma unroll
    for (int tl = 0; tl < 2; ++tl) {
#pragma unroll
        for (int r = 0; r < 4; ++r) {
            const float den = __shfl(nacc[tl][r], denSrc);
            if (rlo < 8) {
                const int trow = q0 + tl * 16 + quad * 4 + r;
                attn_out[(size_t)(b * T_DIM + trow) * E_DIM + h * 8 + rlo] =
                    __float2bfloat16(nacc[tl][r] / den);
            }
        }
    }
}

// ---------------------------------------------------------------------------
// Kernel B: out[4096][512] = attn_bf16 @ W_bf16^T + bias (fp32 out).
// R6's verified version, unchanged: 128x64 tile, BK=64, grid 32x8, XOR-
// swizzled k-chunks (slot kc^(row&7)) for conflict-free b128 frag reads.
// ---------------------------------------------------------------------------
#define BM 128
#define BN 64
#define BK 64

__global__ __launch_bounds__(256, 2)
void combine_gemm(const __hip_bfloat16* __restrict__ A,  // [4096][512]
                  const __hip_bfloat16* __restrict__ Wb, // [512][512] (N,K)
                  const float* __restrict__ bias,        // [512]
                  float* __restrict__ out)               // [4096][512]
{
    __shared__ __hip_bfloat16 As[BM][BK];  // 16 KB
    __shared__ __hip_bfloat16 Bs[BN][BK];  // 8 KB

    const int tid  = threadIdx.x;
    const int lane = tid & 63;
    const int wave = tid >> 6;
    const int bm   = blockIdx.x;          // 0..31
    const int bn   = blockIdx.y;          // 0..7
    const int wm   = (wave & 1) * 64;
    const int wn   = (wave >> 1) * 32;
    const int rlo  = lane & 15;
    const int quad = lane >> 4;

    f32x4 acc[4][2] = {};

    for (int k0 = 0; k0 < E_DIM; k0 += BK) {
        if (k0) __syncthreads();
        // A: 128 rows x 8 chunks(16B) = 1024 chunks, 4 passes of 256.
#pragma unroll
        for (int p = 0; p < 4; ++p) {
            const int c   = p * 256 + tid;
            const int row = c >> 3;
            const int kcs = c & 7;                 // LDS slot
            const int kc  = kcs ^ (row & 7);       // global chunk (swizzle)
            const __hip_bfloat16* gA =
                A + (size_t)(bm * BM + row) * E_DIM + k0 + kc * 8;
            char* lA = (char*)As + (size_t)(p * 256 + wave * 64) * 16;
            __builtin_amdgcn_global_load_lds(
                (const __attribute__((address_space(1))) void*)gA,
                (__attribute__((address_space(3))) void*)lA, 16, 0, 0);
        }
        // B: 64 rows x 8 chunks = 512 chunks, 2 passes of 256.
#pragma unroll
        for (int p = 0; p < 2; ++p) {
            const int c   = p * 256 + tid;
            const int row = c >> 3;
            const int kcs = c & 7;
            const int kc  = kcs ^ (row & 7);
            const __hip_bfloat16* gW =
                Wb + (size_t)(bn * BN + row) * E_DIM + k0 + kc * 8;
            char* lB = (char*)Bs + (size_t)(p * 256 + wave * 64) * 16;
            __builtin_amdgcn_global_load_lds(
                (const __attribute__((address_space(1))) void*)gW,
                (__attribute__((address_space(3))) void*)lB, 16, 0, 0);
        }
        __syncthreads();

#pragma unroll
        for (int ks = 0; ks < 2; ++ks) {
            const int kci  = ks * 4 + quad;              // wanted k-chunk
            const int koff = (kci ^ (rlo & 7)) * 8;      // swizzled LDS off
            bf16x8 af[4], bf[2];
#pragma unroll
            for (int i = 0; i < 4; ++i)
                af[i] = *(const bf16x8*)&As[wm + i * 16 + rlo][koff];
#pragma unroll
            for (int j = 0; j < 2; ++j)
                bf[j] = *(const bf16x8*)&Bs[wn + j * 16 + rlo][koff];
#pragma unroll
            for (int i = 0; i < 4; ++i)
#pragma unroll
                for (int j = 0; j < 2; ++j)
                    acc[i][j] = __builtin_amdgcn_mfma_f32_16x16x32_bf16(
                        af[i], bf[j], acc[i][j], 0, 0, 0);
        }
    }

    // Epilogue: C/D layout col = lane&15, row = quad*4 + reg.
    const int row0 = bm * BM + wm;
    const int col0 = bn * BN + wn;
#pragma unroll
    for (int j = 0; j < 2; ++j) {
        const int col = col0 + j * 16 + rlo;
        const float bv = bias[col];
#pragma unroll
        for (int i = 0; i < 4; ++i) {
            const int rbase = row0 + i * 16 + quad * 4;
#pragma unroll
            for (int r = 0; r < 4; ++r)
                out[(size_t)(rbase + r) * E_DIM + col] = acc[i][j][r] + bv;
        }
    }
}

// ---------------------------------------------------------------------------
extern "C" void kernel_launch(void* const* d_in, const int* in_sizes, int n_in,
                              void* d_out, int out_size, void* d_ws,
                              size_t ws_size, hipStream_t stream)
{
    const float* x     = (const float*)d_in[0];  // [4,1024,512]
    const float* theta = (const float*)d_in[1];  // [8]
    const float* W     = (const float*)d_in[2];  // [512,512]
    const float* bias  = (const float*)d_in[3];  // [512]
    float* out = (float*)d_out;                  // [4,1024,512] fp32

    // ws: attn_bf 4MB | w_bf 512KB | projA_g 4MB | projT_g 4MB  (12.5 MB)
    char* ws = (char*)d_ws;
    __hip_bfloat16* attn_bf = (__hip_bfloat16*)ws;
    __hip_bfloat16* w_bf    = (__hip_bfloat16*)(ws + 4194304);
    __hip_bfloat16* projA_g = (__hip_bfloat16*)(ws + 4718592);
    __hip_bfloat16* projT_g = (__hip_bfloat16*)(ws + 8912896);

    hipLaunchKernelGGL(prep_kernel, dim3(256), dim3(1024), 0, stream,
                       x, theta, W, projA_g, projT_g, w_bf);
    hipLaunchKernelGGL(qattn_mfma, dim3(512), dim3(1024), 0, stream,
                       projA_g, projT_g, attn_bf);
    hipLaunchKernelGGL(combine_gemm, dim3(32, 8), dim3(256), 0, stream,
                       attn_bf, w_bf, bias, out);
}

// Round 10
// 110.397 us; speedup vs baseline: 1.1188x; 1.1188x over previous
//
#include <hip/hip_runtime.h>
#include <hip/hip_bf16.h>
#include <cstdint>
#include <cstddef>

// Problem constants: B=4, T=1024, E=512, H=64, d_k=8
#define T_DIM 1024
#define E_DIM 512

typedef short bf16x8  __attribute__((ext_vector_type(8)));
typedef __bf16 bf16x8h __attribute__((ext_vector_type(8)));
typedef float f32x4   __attribute__((ext_vector_type(4)));
typedef float f32x8   __attribute__((ext_vector_type(8)));

// ---------------------------------------------------------------------------
// Kernel A: MFMA attention, schedule-engineered. grid = 256 heads, 1024 thr
// (R6 config: best measured total; R8/R9 proved occupancy is NOT the binder
// -- VALUBusy pinned ~52% from 16 to 32 waves/CU). The kc-loop body is
// restructured for intra-wave overlap:
//   1. all 8 score MFMAs issued back-to-back (MFMA pipe fills),
//   2. next-kc LDS reads (ka/bv) prefetched before the exp phase,
//   3. exp2 + packed-cvt (v_cvt_pk_bf16_f32 via __builtin_convertvector)
//      + PV MFMA phase overlaps the MFMA-pipe drain.
// Math identical to verified R5-R9: scores via 16x16x32 bf16 MFMA (quad0
// carries d=0..7; projA pre-scaled by sqrt(scale*log2e) so e = exp2(raw
// score)); e-values feed the PV A-operand in the score-MFMA's own
// k-permutation (pi trick, zero cross-lane traffic, zero bank conflicts);
// V B-frag reads projT in the same pi order; B col 8 = ones -> den free in
// output col 8.
// ---------------------------------------------------------------------------
__global__ __launch_bounds__(1024)
void qattn_mfma(const float* __restrict__ x,
                const float* __restrict__ theta,
                const float* __restrict__ W,
                __hip_bfloat16* __restrict__ attn_out, // [4096][512] bf16
                __hip_bfloat16* __restrict__ w_bf)     // [512][512] bf16
{
    __shared__ __hip_bfloat16 projA[T_DIM][8];     // [key][d] scaled, 16 KB
    __shared__ __hip_bfloat16 projT[8][1032];      // [d][key] unscaled, 16.1 KB

    const int head = blockIdx.x;        // 0..255
    const int b    = head >> 6;
    const int h    = head & 63;
    const int tid  = threadIdx.x;       // 0..1023
    const int lane = tid & 63;
    const int wv   = tid >> 6;          // 0..15
    const int rlo  = lane & 15;
    const int quad = lane >> 4;

    // Folded W fp32->bf16 convert: blocks 0..63 cover 512*512/4 threads.
    {
        const int gid = head * 1024 + tid;
        if (gid < 65536) {
            const float4 v = *(const float4*)(W + gid * 4);
            alignas(8) __hip_bfloat16 ob[4] = {
                __float2bfloat16(v.x), __float2bfloat16(v.y),
                __float2bfloat16(v.z), __float2bfloat16(v.w)};
            *(uint2*)(w_bf + gid * 4) = *(const uint2*)ob;
        }
    }

    // sqrt((1/sqrt(8))*log2(e)): folds softmax scale + ln->log2 into the
    // score operands so e = exp2(raw mfma output).
    const float SA = 0.7142255f;
    float ctT[8], ctA[8];
#pragma unroll
    for (int d = 0; d < 8; ++d) {
        ctT[d] = __cosf(theta[d]);
        ctA[d] = ctT[d] * SA;
    }

    // Stage full-head proj: 1024 rows, one per thread.
    const float* xb = x + (size_t)b * T_DIM * E_DIM + h * 8;
    {
        const int r = tid;
        const float4 v0 = *(const float4*)(xb + (size_t)r * E_DIM);
        const float4 v1 = *(const float4*)(xb + (size_t)r * E_DIM + 4);
        float pr[8] = {v0.x, v0.y, v0.z, v0.w, v1.x, v1.y, v1.z, v1.w};
        alignas(16) __hip_bfloat16 ra[8];
#pragma unroll
        for (int d = 0; d < 8; ++d) {
            const float c = __cosf(pr[d]);
            ra[d] = __float2bfloat16(c * ctA[d]);
            projT[d][r] = __float2bfloat16(c * ctT[d]);
        }
        *(uint4*)&projA[r][0] = *(const uint4*)ra;
    }
    __syncthreads();

    const bf16x8 z8 = {};
    bf16x8 ones8;
#pragma unroll
    for (int j = 0; j < 8; ++j) ones8[j] = (short)0x3f80;  // bf16 1.0

    // This wave owns 64 queries (4 tiles of 16).
    const int q0 = wv * 64;
    bf16x8 bq[4];
#pragma unroll
    for (int tl = 0; tl < 4; ++tl)
        bq[tl] = (quad == 0) ? *(const bf16x8*)&projA[q0 + tl * 16 + rlo][0]
                             : z8;

    f32x4 nacc[4] = {};

    // Helper lambda: build V-frag (pi order) for a key chunk base.
    auto load_bv = [&](int key0) -> bf16x8 {
        if (rlo < 8) {
            const __hip_bfloat16* pt = &projT[rlo][key0 + quad * 4];
            union { uint2 u[2]; bf16x8 v; } uu;
            uu.u[0] = *(const uint2*)pt;
            uu.u[1] = *(const uint2*)(pt + 16);
            return uu.v;
        }
        return (rlo == 8) ? ones8 : z8;
    };

    // Prologue: LDS operands for kc=0.
    bf16x8 ka0 = (quad == 0) ? *(const bf16x8*)&projA[rlo][0] : z8;
    bf16x8 ka1 = (quad == 0) ? *(const bf16x8*)&projA[16 + rlo][0] : z8;
    bf16x8 bv  = load_bv(0);

    for (int kc = 0; kc < 32; ++kc) {           // 32-key chunks
        const int key0n = (kc < 31) ? (kc + 1) * 32 : 0;

        // Phase 1: all 8 score MFMAs back-to-back (fills the MFMA pipe).
        f32x4 s0[4], s1[4];
#pragma unroll
        for (int tl = 0; tl < 4; ++tl) {
            s0[tl] = __builtin_amdgcn_mfma_f32_16x16x32_bf16(
                ka0, bq[tl], (f32x4){0.f, 0.f, 0.f, 0.f}, 0, 0, 0);
            s1[tl] = __builtin_amdgcn_mfma_f32_16x16x32_bf16(
                ka1, bq[tl], (f32x4){0.f, 0.f, 0.f, 0.f}, 0, 0, 0);
        }

        // Phase 2: prefetch next chunk's LDS operands (latency hidden
        // under the exp phase below).
        const bf16x8 ka0n =
            (quad == 0) ? *(const bf16x8*)&projA[key0n + rlo][0] : z8;
        const bf16x8 ka1n =
            (quad == 0) ? *(const bf16x8*)&projA[key0n + 16 + rlo][0] : z8;
        const bf16x8 bvn = load_bv(key0n);

        // Phase 3: exp2 + packed cvt + PV (VALU/trans overlap MFMA drain).
#pragma unroll
        for (int tl = 0; tl < 4; ++tl) {
            f32x8 es;
#pragma unroll
            for (int r = 0; r < 4; ++r) {
                es[r]     = __builtin_amdgcn_exp2f(s0[tl][r]);
                es[4 + r] = __builtin_amdgcn_exp2f(s1[tl][r]);
            }
            union { bf16x8h hV; bf16x8 sV; } cv;
            cv.hV = __builtin_convertvector(es, bf16x8h);  // v_cvt_pk_bf16_f32
            nacc[tl] = __builtin_amdgcn_mfma_f32_16x16x32_bf16(
                cv.sV, bv, nacc[tl], 0, 0, 0);
        }

        ka0 = ka0n; ka1 = ka1n; bv = bvn;
    }

    // Epilogue: nacc[tl][r] = num[q=q0+tl*16+quad*4+r][d=rlo]; col 8 = den.
    const int denSrc = (lane & 48) | 8;   // lane with rlo==8 in same quad
#pragma unroll
    for (int tl = 0; tl < 4; ++tl) {
#pragma unroll
        for (int r = 0; r < 4; ++r) {
            const float den = __shfl(nacc[tl][r], denSrc);
            if (rlo < 8) {
                const int trow = q0 + tl * 16 + quad * 4 + r;
                attn_out[(size_t)(b * T_DIM + trow) * E_DIM + h * 8 + rlo] =
                    __float2bfloat16(nacc[tl][r] / den);
            }
        }
    }
}

// ---------------------------------------------------------------------------
// Kernel B: out[4096][512] = attn_bf16 @ W_bf16^T + bias (fp32 out).
// R6's verified version, unchanged: 128x64 tile, BK=64, grid 32x8, XOR-
// swizzled k-chunks (slot kc^(row&7)) for conflict-free b128 frag reads.
// ---------------------------------------------------------------------------
#define BM 128
#define BN 64
#define BK 64

__global__ __launch_bounds__(256, 2)
void combine_gemm(const __hip_bfloat16* __restrict__ A,  // [4096][512]
                  const __hip_bfloat16* __restrict__ Wb, // [512][512] (N,K)
                  const float* __restrict__ bias,        // [512]
                  float* __restrict__ out)               // [4096][512]
{
    __shared__ __hip_bfloat16 As[BM][BK];  // 16 KB
    __shared__ __hip_bfloat16 Bs[BN][BK];  // 8 KB

    const int tid  = threadIdx.x;
    const int lane = tid & 63;
    const int wave = tid >> 6;
    const int bm   = blockIdx.x;          // 0..31
    const int bn   = blockIdx.y;          // 0..7
    const int wm   = (wave & 1) * 64;
    const int wn   = (wave >> 1) * 32;
    const int rlo  = lane & 15;
    const int quad = lane >> 4;

    f32x4 acc[4][2] = {};

    for (int k0 = 0; k0 < E_DIM; k0 += BK) {
        if (k0) __syncthreads();
        // A: 128 rows x 8 chunks(16B) = 1024 chunks, 4 passes of 256.
#pragma unroll
        for (int p = 0; p < 4; ++p) {
            const int c   = p * 256 + tid;
            const int row = c >> 3;
            const int kcs = c & 7;                 // LDS slot
            const int kc  = kcs ^ (row & 7);       // global chunk (swizzle)
            const __hip_bfloat16* gA =
                A + (size_t)(bm * BM + row) * E_DIM + k0 + kc * 8;
            char* lA = (char*)As + (size_t)(p * 256 + wave * 64) * 16;
            __builtin_amdgcn_global_load_lds(
                (const __attribute__((address_space(1))) void*)gA,
                (__attribute__((address_space(3))) void*)lA, 16, 0, 0);
        }
        // B: 64 rows x 8 chunks = 512 chunks, 2 passes of 256.
#pragma unroll
        for (int p = 0; p < 2; ++p) {
            const int c   = p * 256 + tid;
            const int row = c >> 3;
            const int kcs = c & 7;
            const int kc  = kcs ^ (row & 7);
            const __hip_bfloat16* gW =
                Wb + (size_t)(bn * BN + row) * E_DIM + k0 + kc * 8;
            char* lB = (char*)Bs + (size_t)(p * 256 + wave * 64) * 16;
            __builtin_amdgcn_global_load_lds(
                (const __attribute__((address_space(1))) void*)gW,
                (__attribute__((address_space(3))) void*)lB, 16, 0, 0);
        }
        __syncthreads();

#pragma unroll
        for (int ks = 0; ks < 2; ++ks) {
            const int kci  = ks * 4 + quad;              // wanted k-chunk
            const int koff = (kci ^ (rlo & 7)) * 8;      // swizzled LDS off
            bf16x8 af[4], bf[2];
#pragma unroll
            for (int i = 0; i < 4; ++i)
                af[i] = *(const bf16x8*)&As[wm + i * 16 + rlo][koff];
#pragma unroll
            for (int j = 0; j < 2; ++j)
                bf[j] = *(const bf16x8*)&Bs[wn + j * 16 + rlo][koff];
#pragma unroll
            for (int i = 0; i < 4; ++i)
#pragma unroll
                for (int j = 0; j < 2; ++j)
                    acc[i][j] = __builtin_amdgcn_mfma_f32_16x16x32_bf16(
                        af[i], bf[j], acc[i][j], 0, 0, 0);
        }
    }

    // Epilogue: C/D layout col = lane&15, row = quad*4 + reg.
    const int row0 = bm * BM + wm;
    const int col0 = bn * BN + wn;
#pragma unroll
    for (int j = 0; j < 2; ++j) {
        const int col = col0 + j * 16 + rlo;
        const float bv = bias[col];
#pragma unroll
        for (int i = 0; i < 4; ++i) {
            const int rbase = row0 + i * 16 + quad * 4;
#pragma unroll
            for (int r = 0; r < 4; ++r)
                out[(size_t)(rbase + r) * E_DIM + col] = acc[i][j][r] + bv;
        }
    }
}

// ---------------------------------------------------------------------------
extern "C" void kernel_launch(void* const* d_in, const int* in_sizes, int n_in,
                              void* d_out, int out_size, void* d_ws,
                              size_t ws_size, hipStream_t stream)
{
    const float* x     = (const float*)d_in[0];  // [4,1024,512]
    const float* theta = (const float*)d_in[1];  // [8]
    const float* W     = (const float*)d_in[2];  // [512,512]
    const float* bias  = (const float*)d_in[3];  // [512]
    float* out = (float*)d_out;                  // [4,1024,512] fp32

    // ws layout: attn_bf16 [4096*512] = 4 MB, then W_bf16 [512*512] = 512 KB
    __hip_bfloat16* attn_bf = (__hip_bfloat16*)d_ws;
    __hip_bfloat16* w_bf    = (__hip_bfloat16*)((char*)d_ws + 4u * 1024u * 1024u);

    hipLaunchKernelGGL(qattn_mfma, dim3(256), dim3(1024), 0, stream,
                       x, theta, W, attn_bf, w_bf);
    hipLaunchKernelGGL(combine_gemm, dim3(32, 8), dim3(256), 0, stream,
                       attn_bf, w_bf, bias, out);
}

// Round 11
// 102.075 us; speedup vs baseline: 1.2100x; 1.0815x over previous
//
#include <hip/hip_runtime.h>
#include <hip/hip_bf16.h>
#include <cstdint>
#include <cstddef>

// Problem constants: B=4, T=1024, E=512, H=64, d_k=8
#define T_DIM 1024
#define E_DIM 512

typedef short bf16x8 __attribute__((ext_vector_type(8)));
typedef float f32x4  __attribute__((ext_vector_type(4)));

// ---------------------------------------------------------------------------
// Kernel A: MFMA attention with MFMA-fused Schraudolph exp. grid = 256 heads,
// 1024 thr (R6 config). R10 post-mortem: v_exp_f32 at wave64 is ~16 cyc of
// VALU occupancy each -> exp2 was ~2/3 of the per-kc cycle budget and is why
// qattn sat at 45us across every occupancy/schedule variant. Replacement:
//   exp2(x) ~= bitcast_f32(int(2^23*(x+B)))   (Schraudolph, +-3% rel err)
// with BOTH factors folded into existing ops:
//   * 2^23*x : projA pre-scaled by sqrt(2^23*scale*log2e) = 2068.62 so the
//     score MFMA emits t = 2^23*x directly,
//   * 2^23*B : passed as the score-MFMA C operand (BB = 2^23*126.9607,
//     minimax B plus half-ulp truncation compensation),
//   * bf16(e) = top 16 bits of int(t): one v_cvt_i32_f32 per value plus one
//     v_perm_b32 per pair. ~3 cyc/e vs ~17 cyc/e for exp2+cvt_pk.
// fp32 rounding at 2^30 inside the MFMA accumulation costs <=3e-5 in the
// exponent (negligible vs the 3% approx error).
// Rest identical to verified R5-R10: scores via 16x16x32 bf16 MFMA (quad0
// carries d=0..7); e-values feed the PV A-operand in the score-MFMA's own
// k-permutation (pi trick, zero cross-lane traffic, zero bank conflicts);
// V B-frag reads projT (unscaled) in the same pi order; B col 8 = ones ->
// den free in output col 8; no max-subtraction needed (|score|<=2.83).
// ---------------------------------------------------------------------------
__global__ __launch_bounds__(1024)
void qattn_mfma(const float* __restrict__ x,
                const float* __restrict__ theta,
                const float* __restrict__ W,
                __hip_bfloat16* __restrict__ attn_out, // [4096][512] bf16
                __hip_bfloat16* __restrict__ w_bf)     // [512][512] bf16
{
    __shared__ __hip_bfloat16 projA[T_DIM][8];     // [key][d] scaled, 16 KB
    __shared__ __hip_bfloat16 projT[8][1032];      // [d][key] unscaled, 16.1 KB

    const int head = blockIdx.x;        // 0..255
    const int b    = head >> 6;
    const int h    = head & 63;
    const int tid  = threadIdx.x;       // 0..1023
    const int lane = tid & 63;
    const int wv   = tid >> 6;          // 0..15
    const int rlo  = lane & 15;
    const int quad = lane >> 4;

    // Folded W fp32->bf16 convert: blocks 0..63 cover 512*512/4 threads.
    {
        const int gid = head * 1024 + tid;
        if (gid < 65536) {
            const float4 v = *(const float4*)(W + gid * 4);
            alignas(8) __hip_bfloat16 ob[4] = {
                __float2bfloat16(v.x), __float2bfloat16(v.y),
                __float2bfloat16(v.z), __float2bfloat16(v.w)};
            *(uint2*)(w_bf + gid * 4) = *(const uint2*)ob;
        }
    }

    // sqrt(2^23 * (1/sqrt(8)) * log2(e)) = 0.7142255 * 2^11.5: score MFMA
    // output becomes t = 2^23 * x where x is the exp2 argument.
    const float SA2 = 0.7142255f * 2896.3093f;   // ~2068.62
    float ctT[8], ctA[8];
#pragma unroll
    for (int d = 0; d < 8; ++d) {
        ctT[d] = __cosf(theta[d]);
        ctA[d] = ctT[d] * SA2;
    }

    // Stage full-head proj: 1024 rows, one per thread.
    const float* xb = x + (size_t)b * T_DIM * E_DIM + h * 8;
    {
        const int r = tid;
        const float4 v0 = *(const float4*)(xb + (size_t)r * E_DIM);
        const float4 v1 = *(const float4*)(xb + (size_t)r * E_DIM + 4);
        float pr[8] = {v0.x, v0.y, v0.z, v0.w, v1.x, v1.y, v1.z, v1.w};
        alignas(16) __hip_bfloat16 ra[8];
#pragma unroll
        for (int d = 0; d < 8; ++d) {
            const float c = __cosf(pr[d]);
            ra[d] = __float2bfloat16(c * ctA[d]);
            projT[d][r] = __float2bfloat16(c * ctT[d]);
        }
        *(uint4*)&projA[r][0] = *(const uint4*)ra;
    }
    __syncthreads();

    const bf16x8 z8 = {};
    bf16x8 ones8;
#pragma unroll
    for (int j = 0; j < 8; ++j) ones8[j] = (short)0x3f80;  // bf16 1.0

    // Schraudolph bias in the C operand: 2^23 * 126.9607
    // (B = 127 - log2(1.0617)/2 minimax, + 2^-9 truncation compensation).
    const float BB = 1.0650235e9f;
    const f32x4 cinit = {BB, BB, BB, BB};

    // This wave owns 64 queries (4 tiles of 16).
    const int q0 = wv * 64;
    bf16x8 bq[4];
#pragma unroll
    for (int tl = 0; tl < 4; ++tl)
        bq[tl] = (quad == 0) ? *(const bf16x8*)&projA[q0 + tl * 16 + rlo][0]
                             : z8;

    f32x4 nacc[4] = {};

    // Helper: build V-frag (pi order) for a key chunk base.
    auto load_bv = [&](int key0) -> bf16x8 {
        if (rlo < 8) {
            const __hip_bfloat16* pt = &projT[rlo][key0 + quad * 4];
            union { uint2 u[2]; bf16x8 v; } uu;
            uu.u[0] = *(const uint2*)pt;
            uu.u[1] = *(const uint2*)(pt + 16);
            return uu.v;
        }
        return (rlo == 8) ? ones8 : z8;
    };

    // Prologue: LDS operands for kc=0.
    bf16x8 ka0 = (quad == 0) ? *(const bf16x8*)&projA[rlo][0] : z8;
    bf16x8 ka1 = (quad == 0) ? *(const bf16x8*)&projA[16 + rlo][0] : z8;
    bf16x8 bv  = load_bv(0);

    for (int kc = 0; kc < 32; ++kc) {           // 32-key chunks
        const int key0n = (kc < 31) ? (kc + 1) * 32 : 0;

        // Phase 1: all 8 score MFMAs back-to-back (C = Schraudolph bias).
        f32x4 s0[4], s1[4];
#pragma unroll
        for (int tl = 0; tl < 4; ++tl) {
            s0[tl] = __builtin_amdgcn_mfma_f32_16x16x32_bf16(
                ka0, bq[tl], cinit, 0, 0, 0);
            s1[tl] = __builtin_amdgcn_mfma_f32_16x16x32_bf16(
                ka1, bq[tl], cinit, 0, 0, 0);
        }

        // Phase 2: prefetch next chunk's LDS operands.
        const bf16x8 ka0n =
            (quad == 0) ? *(const bf16x8*)&projA[key0n + rlo][0] : z8;
        const bf16x8 ka1n =
            (quad == 0) ? *(const bf16x8*)&projA[key0n + 16 + rlo][0] : z8;
        const bf16x8 bvn = load_bv(key0n);

        // Phase 3: Schraudolph pack (cvt + perm) + PV MFMA.
        // t = 2^23*(x+B) in [1.03e9, 1.10e9]; bf16(e) = int(t) >> 16.
        // perm(S0=hi, S1=lo, 0x07060302): D = {hi[31:16], lo[31:16]}.
#pragma unroll
        for (int tl = 0; tl < 4; ++tl) {
            const uint32_t i0 = (uint32_t)(int)s0[tl][0];
            const uint32_t i1 = (uint32_t)(int)s0[tl][1];
            const uint32_t i2 = (uint32_t)(int)s0[tl][2];
            const uint32_t i3 = (uint32_t)(int)s0[tl][3];
            const uint32_t j0 = (uint32_t)(int)s1[tl][0];
            const uint32_t j1 = (uint32_t)(int)s1[tl][1];
            const uint32_t j2 = (uint32_t)(int)s1[tl][2];
            const uint32_t j3 = (uint32_t)(int)s1[tl][3];
            union { uint32_t u[4]; bf16x8 v; } pk;
            pk.u[0] = __builtin_amdgcn_perm(i1, i0, 0x07060302u);
            pk.u[1] = __builtin_amdgcn_perm(i3, i2, 0x07060302u);
            pk.u[2] = __builtin_amdgcn_perm(j1, j0, 0x07060302u);
            pk.u[3] = __builtin_amdgcn_perm(j3, j2, 0x07060302u);
            nacc[tl] = __builtin_amdgcn_mfma_f32_16x16x32_bf16(
                pk.v, bv, nacc[tl], 0, 0, 0);
        }

        ka0 = ka0n; ka1 = ka1n; bv = bvn;
    }

    // Epilogue: nacc[tl][r] = num[q=q0+tl*16+quad*4+r][d=rlo]; col 8 = den.
    const int denSrc = (lane & 48) | 8;   // lane with rlo==8 in same quad
#pragma unroll
    for (int tl = 0; tl < 4; ++tl) {
#pragma unroll
        for (int r = 0; r < 4; ++r) {
            const float den = __shfl(nacc[tl][r], denSrc);
            if (rlo < 8) {
                const int trow = q0 + tl * 16 + quad * 4 + r;
                attn_out[(size_t)(b * T_DIM + trow) * E_DIM + h * 8 + rlo] =
                    __float2bfloat16(nacc[tl][r] / den);
            }
        }
    }
}

// ---------------------------------------------------------------------------
// Kernel B: out[4096][512] = attn_bf16 @ W_bf16^T + bias (fp32 out).
// R6's verified version, unchanged: 128x64 tile, BK=64, grid 32x8, XOR-
// swizzled k-chunks (slot kc^(row&7)) for conflict-free b128 frag reads.
// ---------------------------------------------------------------------------
#define BM 128
#define BN 64
#define BK 64

__global__ __launch_bounds__(256, 2)
void combine_gemm(const __hip_bfloat16* __restrict__ A,  // [4096][512]
                  const __hip_bfloat16* __restrict__ Wb, // [512][512] (N,K)
                  const float* __restrict__ bias,        // [512]
                  float* __restrict__ out)               // [4096][512]
{
    __shared__ __hip_bfloat16 As[BM][BK];  // 16 KB
    __shared__ __hip_bfloat16 Bs[BN][BK];  // 8 KB

    const int tid  = threadIdx.x;
    const int lane = tid & 63;
    const int wave = tid >> 6;
    const int bm   = blockIdx.x;          // 0..31
    const int bn   = blockIdx.y;          // 0..7
    const int wm   = (wave & 1) * 64;
    const int wn   = (wave >> 1) * 32;
    const int rlo  = lane & 15;
    const int quad = lane >> 4;

    f32x4 acc[4][2] = {};

    for (int k0 = 0; k0 < E_DIM; k0 += BK) {
        if (k0) __syncthreads();
        // A: 128 rows x 8 chunks(16B) = 1024 chunks, 4 passes of 256.
#pragma unroll
        for (int p = 0; p < 4; ++p) {
            const int c   = p * 256 + tid;
            const int row = c >> 3;
            const int kcs = c & 7;                 // LDS slot
            const int kc  = kcs ^ (row & 7);       // global chunk (swizzle)
            const __hip_bfloat16* gA =
                A + (size_t)(bm * BM + row) * E_DIM + k0 + kc * 8;
            char* lA = (char*)As + (size_t)(p * 256 + wave * 64) * 16;
            __builtin_amdgcn_global_load_lds(
                (const __attribute__((address_space(1))) void*)gA,
                (__attribute__((address_space(3))) void*)lA, 16, 0, 0);
        }
        // B: 64 rows x 8 chunks = 512 chunks, 2 passes of 256.
#pragma unroll
        for (int p = 0; p < 2; ++p) {
            const int c   = p * 256 + tid;
            const int row = c >> 3;
            const int kcs = c & 7;
            const int kc  = kcs ^ (row & 7);
            const __hip_bfloat16* gW =
                Wb + (size_t)(bn * BN + row) * E_DIM + k0 + kc * 8;
            char* lB = (char*)Bs + (size_t)(p * 256 + wave * 64) * 16;
            __builtin_amdgcn_global_load_lds(
                (const __attribute__((address_space(1))) void*)gW,
                (__attribute__((address_space(3))) void*)lB, 16, 0, 0);
        }
        __syncthreads();

#pragma unroll
        for (int ks = 0; ks < 2; ++ks) {
            const int kci  = ks * 4 + quad;              // wanted k-chunk
            const int koff = (kci ^ (rlo & 7)) * 8;      // swizzled LDS off
            bf16x8 af[4], bf[2];
#pragma unroll
            for (int i = 0; i < 4; ++i)
                af[i] = *(const bf16x8*)&As[wm + i * 16 + rlo][koff];
#pragma unroll
            for (int j = 0; j < 2; ++j)
                bf[j] = *(const bf16x8*)&Bs[wn + j * 16 + rlo][koff];
#pragma unroll
            for (int i = 0; i < 4; ++i)
#pragma unroll
                for (int j = 0; j < 2; ++j)
                    acc[i][j] = __builtin_amdgcn_mfma_f32_16x16x32_bf16(
                        af[i], bf[j], acc[i][j], 0, 0, 0);
        }
    }

    // Epilogue: C/D layout col = lane&15, row = quad*4 + reg.
    const int row0 = bm * BM + wm;
    const int col0 = bn * BN + wn;
#pragma unroll
    for (int j = 0; j < 2; ++j) {
        const int col = col0 + j * 16 + rlo;
        const float bv = bias[col];
#pragma unroll
        for (int i = 0; i < 4; ++i) {
            const int rbase = row0 + i * 16 + quad * 4;
#pragma unroll
            for (int r = 0; r < 4; ++r)
                out[(size_t)(rbase + r) * E_DIM + col] = acc[i][j][r] + bv;
        }
    }
}

// ---------------------------------------------------------------------------
extern "C" void kernel_launch(void* const* d_in, const int* in_sizes, int n_in,
                              void* d_out, int out_size, void* d_ws,
                              size_t ws_size, hipStream_t stream)
{
    const float* x     = (const float*)d_in[0];  // [4,1024,512]
    const float* theta = (const float*)d_in[1];  // [8]
    const float* W     = (const float*)d_in[2];  // [512,512]
    const float* bias  = (const float*)d_in[3];  // [512]
    float* out = (float*)d_out;                  // [4,1024,512] fp32

    // ws layout: attn_bf16 [4096*512] = 4 MB, then W_bf16 [512*512] = 512 KB
    __hip_bfloat16* attn_bf = (__hip_bfloat16*)d_ws;
    __hip_bfloat16* w_bf    = (__hip_bfloat16*)((char*)d_ws + 4u * 1024u * 1024u);

    hipLaunchKernelGGL(qattn_mfma, dim3(256), dim3(1024), 0, stream,
                       x, theta, W, attn_bf, w_bf);
    hipLaunchKernelGGL(combine_gemm, dim3(32, 8), dim3(256), 0, stream,
                       attn_bf, w_bf, bias, out);
}